// Round 1
// baseline (329.865 us; speedup 1.0000x reference)
//
#include <hip/hip_runtime.h>
#include <hip/hip_bf16.h>
#include <math.h>

typedef __bf16 bf16x8 __attribute__((ext_vector_type(8)));
typedef __bf16 bf16x4 __attribute__((ext_vector_type(4)));
typedef float f32x4 __attribute__((ext_vector_type(4)));

#define N_TOK 4096
#define EDIM 512
#define NHEAD 8
#define HD 64
#define LDQKV 1536
#define LDCOMB 896

// ---------------- fp32 -> bf16 convert (vectorized by 4) ----------------
__global__ void cvt_kernel(const float* __restrict__ in, __bf16* __restrict__ out, int n4) {
    int i = blockIdx.x * blockDim.x + threadIdx.x;
    if (i < n4) {
        const float4 v = ((const float4*)in)[i];
        bf16x4 o;
        o[0] = (__bf16)v.x; o[1] = (__bf16)v.y; o[2] = (__bf16)v.z; o[3] = (__bf16)v.w;
        ((bf16x4*)out)[i] = o;
    }
}

// ---------------- generic NT bf16 MFMA GEMM: C = A * B^T + bias ----------------
// A [M,K] row-major bf16, B [N,K] row-major bf16. OUT_MODE 0: f32 C, 1: bf16 C.
template<int OUT_MODE>
__global__ __launch_bounds__(256) void gemm_nt(const __bf16* __restrict__ A, int lda,
                                               const __bf16* __restrict__ B, int ldb,
                                               const float* __restrict__ bias,
                                               void* __restrict__ C, int ldc,
                                               int K) {
    __shared__ __attribute__((aligned(16))) __bf16 As[128][40];  // +8 pad: stride 80B
    __shared__ __attribute__((aligned(16))) __bf16 Bs[128][40];
    const int tid = threadIdx.x;
    const int wave = tid >> 6, lane = tid & 63;
    const int wm = (wave >> 1) * 64, wn = (wave & 1) * 64;
    const int bm = blockIdx.x * 128, bn = blockIdx.y * 128;
    const int lr = lane & 15, lq = lane >> 4;

    f32x4 acc[4][4] = {};

    for (int k0 = 0; k0 < K; k0 += 32) {
        __syncthreads();
        #pragma unroll
        for (int c = tid; c < 512; c += 256) {
            const int row = c >> 2, k8 = (c & 3) * 8;
            *(bf16x8*)&As[row][k8] = *(const bf16x8*)&A[(size_t)(bm + row) * lda + k0 + k8];
            *(bf16x8*)&Bs[row][k8] = *(const bf16x8*)&B[(size_t)(bn + row) * ldb + k0 + k8];
        }
        __syncthreads();
        bf16x8 af[4], bfr[4];
        #pragma unroll
        for (int i = 0; i < 4; i++) {
            af[i]  = *(const bf16x8*)&As[wm + i * 16 + lr][lq * 8];
            bfr[i] = *(const bf16x8*)&Bs[wn + i * 16 + lr][lq * 8];
        }
        #pragma unroll
        for (int i = 0; i < 4; i++)
            #pragma unroll
            for (int j = 0; j < 4; j++)
                acc[i][j] = __builtin_amdgcn_mfma_f32_16x16x32_bf16(af[i], bfr[j], acc[i][j], 0, 0, 0);
    }

    #pragma unroll
    for (int i = 0; i < 4; i++) {
        #pragma unroll
        for (int j = 0; j < 4; j++) {
            const int col = bn + wn + j * 16 + lr;
            const float bv = bias[col];
            #pragma unroll
            for (int r = 0; r < 4; r++) {
                const int row = bm + wm + i * 16 + lq * 4 + r;
                const float v = acc[i][j][r] + bv;
                if (OUT_MODE == 0) ((float*)C)[(size_t)row * ldc + col] = v;
                else               ((__bf16*)C)[(size_t)row * ldc + col] = (__bf16)v;
            }
        }
    }
}

// ---------------- flash attention with step mask ----------------
// qkv bf16 [4096][1536]; block = (64 queries, 1 head); 4 waves x 16 queries.
__global__ __launch_bounds__(256) void attn_kernel(const __bf16* __restrict__ qkv,
                                                   const int* __restrict__ steps,
                                                   __bf16* __restrict__ ctx) {
    __shared__ __attribute__((aligned(16))) __bf16 Ks[128][72];   // [key][d], +8 pad
    __shared__ __attribute__((aligned(16))) __bf16 Vt[64][136];   // [d][key], +8 pad
    __shared__ __attribute__((aligned(16))) __bf16 Ps[64][136];   // per-wave 16-row bands
    __shared__ int kst[128];

    const int h = blockIdx.y;
    const int tid = threadIdx.x, wave = tid >> 6, lane = tid & 63;
    const int lr = lane & 15, lq = lane >> 4;
    const int qbase = blockIdx.x * 64 + wave * 16;

    // Q fragments (A-operand): m = lr (query), k = lq*8+j (+32*ks)
    bf16x8 aq[2];
    {
        const __bf16* qrow = qkv + (size_t)(qbase + lr) * LDQKV + h * HD;
        aq[0] = *(const bf16x8*)&qrow[lq * 8];
        aq[1] = *(const bf16x8*)&qrow[32 + lq * 8];
    }
    int qstep[4];
    #pragma unroll
    for (int r = 0; r < 4; r++) qstep[r] = steps[qbase + lq * 4 + r];

    float m_i[4], l_i[4];
    #pragma unroll
    for (int r = 0; r < 4; r++) { m_i[r] = -3e38f; l_i[r] = 0.f; }
    f32x4 o[4] = {};

    for (int kt = 0; kt < N_TOK; kt += 128) {
        __syncthreads();
        // stage K tile [128][64]
        #pragma unroll
        for (int c = tid; c < 1024; c += 256) {
            const int row = c >> 3, k8 = (c & 7) * 8;
            *(bf16x8*)&Ks[row][k8] =
                *(const bf16x8*)&qkv[(size_t)(kt + row) * LDQKV + EDIM + h * HD + k8];
        }
        // stage V transposed [64 d][128 key]
        #pragma unroll
        for (int c = tid; c < 1024; c += 256) {
            const int row = c >> 3, d8 = (c & 7) * 8;
            bf16x8 vv = *(const bf16x8*)&qkv[(size_t)(kt + row) * LDQKV + 2 * EDIM + h * HD + d8];
            #pragma unroll
            for (int i = 0; i < 8; i++) Vt[d8 + i][row] = vv[i];
        }
        if (tid < 128) kst[tid] = steps[kt + tid];
        __syncthreads();

        // S = Q K^T  (rows=queries, cols=keys)
        f32x4 s[8];
        #pragma unroll
        for (int t = 0; t < 8; t++) {
            bf16x8 b0 = *(const bf16x8*)&Ks[t * 16 + lr][lq * 8];
            bf16x8 b1 = *(const bf16x8*)&Ks[t * 16 + lr][32 + lq * 8];
            f32x4 a = {};
            a = __builtin_amdgcn_mfma_f32_16x16x32_bf16(aq[0], b0, a, 0, 0, 0);
            a = __builtin_amdgcn_mfma_f32_16x16x32_bf16(aq[1], b1, a, 0, 0, 0);
            s[t] = a;
        }
        // scale + mask + running max
        float mnew[4];
        #pragma unroll
        for (int r = 0; r < 4; r++) mnew[r] = m_i[r];
        #pragma unroll
        for (int t = 0; t < 8; t++) {
            const int kstep = kst[t * 16 + lr];
            #pragma unroll
            for (int r = 0; r < 4; r++) {
                float v = s[t][r] * 0.125f;
                if (kstep < qstep[r]) v = -1e9f;
                s[t][r] = v;
                mnew[r] = fmaxf(mnew[r], v);
            }
        }
        #pragma unroll
        for (int r = 0; r < 4; r++) {
            float v = mnew[r];
            v = fmaxf(v, __shfl_xor(v, 1));
            v = fmaxf(v, __shfl_xor(v, 2));
            v = fmaxf(v, __shfl_xor(v, 4));
            v = fmaxf(v, __shfl_xor(v, 8));
            mnew[r] = v;
        }
        // online softmax update
        #pragma unroll
        for (int r = 0; r < 4; r++) {
            const float a = __expf(m_i[r] - mnew[r]);
            m_i[r] = mnew[r];
            float sum = 0.f;
            #pragma unroll
            for (int t = 0; t < 8; t++) {
                const float p = __expf(s[t][r] - mnew[r]);
                s[t][r] = p;
                sum += p;
            }
            sum += __shfl_xor(sum, 1);
            sum += __shfl_xor(sum, 2);
            sum += __shfl_xor(sum, 4);
            sum += __shfl_xor(sum, 8);
            l_i[r] = l_i[r] * a + sum;
            #pragma unroll
            for (int dt = 0; dt < 4; dt++) o[dt][r] *= a;
        }
        // P (C-layout) -> LDS, wave-private band
        #pragma unroll
        for (int t = 0; t < 8; t++)
            #pragma unroll
            for (int r = 0; r < 4; r++)
                Ps[wave * 16 + lq * 4 + r][t * 16 + lr] = (__bf16)s[t][r];
        // O += P V   (A = P[q][key], B = V^T[d][key])
        #pragma unroll
        for (int ks2 = 0; ks2 < 4; ks2++) {
            bf16x8 ap = *(const bf16x8*)&Ps[wave * 16 + lr][ks2 * 32 + lq * 8];
            #pragma unroll
            for (int dt = 0; dt < 4; dt++) {
                bf16x8 bv = *(const bf16x8*)&Vt[dt * 16 + lr][ks2 * 32 + lq * 8];
                o[dt] = __builtin_amdgcn_mfma_f32_16x16x32_bf16(ap, bv, o[dt], 0, 0, 0);
            }
        }
    }
    // epilogue: ctx[n][h*64 + d]
    #pragma unroll
    for (int dt = 0; dt < 4; dt++)
        #pragma unroll
        for (int r = 0; r < 4; r++) {
            const float v = o[dt][r] / l_i[lq * 0 + r];
            ctx[(size_t)(qbase + lq * 4 + r) * EDIM + h * HD + dt * 16 + lr] = (__bf16)v;
        }
}

// ---------------- embeddings: combined cols [512, 896) ----------------
__global__ void embed_kernel(const int* __restrict__ dmask, const int* __restrict__ steps,
                             const float* __restrict__ status, __bf16* __restrict__ combined) {
    const int n = blockIdx.x;
    const int c = threadIdx.x;               // 0..383
    const int st = min(max(steps[n], 0), 99);
    float v;
    if (c < 128) {
        v = status[dmask[n] * 128 + c];
    } else {
        const int c2 = c - 128;
        const int p = c2 >> 1;
        const float div = expf((float)(2 * p) * (-9.210340371976184f / 256.0f));
        const float ang = (float)st * div;
        v = (c2 & 1) ? cosf(ang) : sinf(ang);
    }
    combined[(size_t)n * LDCOMB + EDIM + c] = (__bf16)v;
}

// ---------------- LayerNorm + ReLU + residual ----------------
__global__ __launch_bounds__(256) void ln_kernel(const float* __restrict__ h,
                                                 const float* __restrict__ x,
                                                 const float* __restrict__ gamma,
                                                 const float* __restrict__ beta,
                                                 float* __restrict__ out) {
    const int row = blockIdx.x * 4 + (threadIdx.x >> 6);
    const int lane = threadIdx.x & 63;
    const float* hr = h + (size_t)row * EDIM;
    float4 v0 = ((const float4*)hr)[lane];
    float4 v1 = ((const float4*)hr)[64 + lane];
    float sum = v0.x + v0.y + v0.z + v0.w + v1.x + v1.y + v1.z + v1.w;
    float sq = v0.x * v0.x + v0.y * v0.y + v0.z * v0.z + v0.w * v0.w +
               v1.x * v1.x + v1.y * v1.y + v1.z * v1.z + v1.w * v1.w;
    #pragma unroll
    for (int m = 1; m < 64; m <<= 1) {
        sum += __shfl_xor(sum, m);
        sq  += __shfl_xor(sq, m);
    }
    const float mean = sum * (1.0f / EDIM);
    const float var = sq * (1.0f / EDIM) - mean * mean;
    const float rstd = rsqrtf(var + 1e-5f);
    const float* xr = x + (size_t)row * EDIM;
    float* orow = out + (size_t)row * EDIM;
    #pragma unroll
    for (int half = 0; half < 2; half++) {
        const float4 v = half ? v1 : v0;
        const int cb = half * 256 + lane * 4;
        float4 res;
        const float* vp = (const float*)&v;
        float tmp[4];
        #pragma unroll
        for (int i = 0; i < 4; i++) {
            const int c = cb + i;
            float t = (vp[i] - mean) * rstd * gamma[c] + beta[c];
            t = fmaxf(t, 0.f);
            tmp[i] = xr[c] + t;
        }
        res.x = tmp[0]; res.y = tmp[1]; res.z = tmp[2]; res.w = tmp[3];
        ((float4*)orow)[cb >> 2] = res;
    }
}

// ---------------- launch ----------------
extern "C" void kernel_launch(void* const* d_in, const int* in_sizes, int n_in,
                              void* d_out, int out_size, void* d_ws, size_t ws_size,
                              hipStream_t stream) {
    const float* x      = (const float*)d_in[0];
    const int*   dmask  = (const int*)d_in[1];
    const int*   steps  = (const int*)d_in[2];
    const float* status = (const float*)d_in[3];
    const float* w_in   = (const float*)d_in[4];
    const float* b_in   = (const float*)d_in[5];
    const float* w_out  = (const float*)d_in[6];
    const float* b_out  = (const float*)d_in[7];
    const float* w_mlp  = (const float*)d_in[8];
    const float* b_mlp  = (const float*)d_in[9];
    const float* gamma  = (const float*)d_in[10];
    const float* beta   = (const float*)d_in[11];
    float* out = (float*)d_out;

    char* ws = (char*)d_ws;
    size_t off = 0;
    auto alloc = [&](size_t bytes) {
        void* p = ws + off;
        off = (off + bytes + 255) & ~(size_t)255;
        return p;
    };
    __bf16* x_bf    = (__bf16*)alloc((size_t)N_TOK * EDIM * 2);
    __bf16* wqkv_bf = (__bf16*)alloc((size_t)3 * EDIM * EDIM * 2);
    __bf16* wout_bf = (__bf16*)alloc((size_t)EDIM * EDIM * 2);
    __bf16* wmlp_bf = (__bf16*)alloc((size_t)EDIM * LDCOMB * 2);
    __bf16* qkv_bf  = (__bf16*)alloc((size_t)N_TOK * LDQKV * 2);
    __bf16* ctx_bf  = (__bf16*)alloc((size_t)N_TOK * EDIM * 2);
    __bf16* comb_bf = (__bf16*)alloc((size_t)N_TOK * LDCOMB * 2);
    float*  h_f32   = (float*)alloc((size_t)N_TOK * EDIM * 4);

    // converts
    {
        int n4 = N_TOK * EDIM / 4;
        cvt_kernel<<<(n4 + 255) / 256, 256, 0, stream>>>(x, x_bf, n4);
        n4 = 3 * EDIM * EDIM / 4;
        cvt_kernel<<<(n4 + 255) / 256, 256, 0, stream>>>(w_in, wqkv_bf, n4);
        n4 = EDIM * EDIM / 4;
        cvt_kernel<<<(n4 + 255) / 256, 256, 0, stream>>>(w_out, wout_bf, n4);
        n4 = EDIM * LDCOMB / 4;
        cvt_kernel<<<(n4 + 255) / 256, 256, 0, stream>>>(w_mlp, wmlp_bf, n4);
    }
    // qkv = x @ w_in^T + b_in   -> bf16 [4096][1536]
    gemm_nt<1><<<dim3(N_TOK / 128, 3 * EDIM / 128), 256, 0, stream>>>(
        x_bf, EDIM, wqkv_bf, EDIM, b_in, qkv_bf, LDQKV, EDIM);
    // attention -> ctx bf16 [4096][512]
    attn_kernel<<<dim3(N_TOK / 64, NHEAD), 256, 0, stream>>>(qkv_bf, steps, ctx_bf);
    // x_att = ctx @ w_out^T + b_out -> combined cols [0,512)
    gemm_nt<1><<<dim3(N_TOK / 128, EDIM / 128), 256, 0, stream>>>(
        ctx_bf, EDIM, wout_bf, EDIM, b_out, comb_bf, LDCOMB, EDIM);
    // embeddings -> combined cols [512,896)
    embed_kernel<<<N_TOK, 384, 0, stream>>>(dmask, steps, status, comb_bf);
    // h = combined @ w_mlp^T + b_mlp -> f32 [4096][512]
    gemm_nt<0><<<dim3(N_TOK / 128, EDIM / 128), 256, 0, stream>>>(
        comb_bf, LDCOMB, wmlp_bf, LDCOMB, b_mlp, h_f32, EDIM, LDCOMB);
    // LN + ReLU + residual
    ln_kernel<<<N_TOK / 4, 256, 0, stream>>>(h_f32, x, gamma, beta, out);
}

// Round 2
// 310.325 us; speedup vs baseline: 1.0630x; 1.0630x over previous
//
#include <hip/hip_runtime.h>
#include <hip/hip_bf16.h>
#include <math.h>

typedef __bf16 bf16x8 __attribute__((ext_vector_type(8)));
typedef __bf16 bf16x4 __attribute__((ext_vector_type(4)));
typedef float f32x4 __attribute__((ext_vector_type(4)));

#define N_TOK 4096
#define EDIM 512
#define NHEAD 8
#define HD 64
#define LDQKV 1536
#define LDCOMB 896

// ---------------- fp32 -> bf16 convert, 4 arrays fused ----------------
__global__ void cvt4_kernel(const float* __restrict__ s0, __bf16* __restrict__ d0, int n0,
                            const float* __restrict__ s1, __bf16* __restrict__ d1, int n1,
                            const float* __restrict__ s2, __bf16* __restrict__ d2, int n2,
                            const float* __restrict__ s3, __bf16* __restrict__ d3, int n3) {
    int i = blockIdx.x * blockDim.x + threadIdx.x;
    const float* src; __bf16* dst;
    if (i < n0)                { src = s0; dst = d0; }
    else if (i < n0 + n1)      { i -= n0; src = s1; dst = d1; }
    else if (i < n0 + n1 + n2) { i -= n0 + n1; src = s2; dst = d2; }
    else if (i < n0 + n1 + n2 + n3) { i -= n0 + n1 + n2; src = s3; dst = d3; }
    else return;
    const float4 v = ((const float4*)src)[i];
    bf16x4 o;
    o[0] = (__bf16)v.x; o[1] = (__bf16)v.y; o[2] = (__bf16)v.z; o[3] = (__bf16)v.w;
    ((bf16x4*)dst)[i] = o;
}

// ---------------- generic NT bf16 MFMA GEMM: C = A * B^T + bias ----------------
template<int OUT_MODE>
__global__ __launch_bounds__(256) void gemm_nt(const __bf16* __restrict__ A, int lda,
                                               const __bf16* __restrict__ B, int ldb,
                                               const float* __restrict__ bias,
                                               void* __restrict__ C, int ldc,
                                               int K) {
    __shared__ __attribute__((aligned(16))) __bf16 As[128][40];
    __shared__ __attribute__((aligned(16))) __bf16 Bs[128][40];
    const int tid = threadIdx.x;
    const int wave = tid >> 6, lane = tid & 63;
    const int wm = (wave >> 1) * 64, wn = (wave & 1) * 64;
    const int bm = blockIdx.x * 128, bn = blockIdx.y * 128;
    const int lr = lane & 15, lq = lane >> 4;

    f32x4 acc[4][4] = {};

    for (int k0 = 0; k0 < K; k0 += 32) {
        __syncthreads();
        #pragma unroll
        for (int c = tid; c < 512; c += 256) {
            const int row = c >> 2, k8 = (c & 3) * 8;
            *(bf16x8*)&As[row][k8] = *(const bf16x8*)&A[(size_t)(bm + row) * lda + k0 + k8];
            *(bf16x8*)&Bs[row][k8] = *(const bf16x8*)&B[(size_t)(bn + row) * ldb + k0 + k8];
        }
        __syncthreads();
        bf16x8 af[4], bfr[4];
        #pragma unroll
        for (int i = 0; i < 4; i++) {
            af[i]  = *(const bf16x8*)&As[wm + i * 16 + lr][lq * 8];
            bfr[i] = *(const bf16x8*)&Bs[wn + i * 16 + lr][lq * 8];
        }
        #pragma unroll
        for (int i = 0; i < 4; i++)
            #pragma unroll
            for (int j = 0; j < 4; j++)
                acc[i][j] = __builtin_amdgcn_mfma_f32_16x16x32_bf16(af[i], bfr[j], acc[i][j], 0, 0, 0);
    }

    #pragma unroll
    for (int i = 0; i < 4; i++) {
        #pragma unroll
        for (int j = 0; j < 4; j++) {
            const int col = bn + wn + j * 16 + lr;
            const float bv = bias[col];
            #pragma unroll
            for (int r = 0; r < 4; r++) {
                const int row = bm + wm + i * 16 + lq * 4 + r;
                const float v = acc[i][j][r] + bv;
                if (OUT_MODE == 0) ((float*)C)[(size_t)row * ldc + col] = v;
                else               ((__bf16*)C)[(size_t)row * ldc + col] = (__bf16)v;
            }
        }
    }
}

// ---------------- V transpose: vt[h*64+d][n] = qkv[n][2E + h*64 + d] ----------------
__global__ __launch_bounds__(256) void transpose_v(const __bf16* __restrict__ qkv,
                                                   __bf16* __restrict__ vt) {
    __shared__ __attribute__((aligned(16))) __bf16 T[64][72];
    const int h = blockIdx.y;
    const int n0 = blockIdx.x * 64;
    const int tid = threadIdx.x;
    #pragma unroll
    for (int c = tid; c < 512; c += 256) {
        const int r = c >> 3, d8 = (c & 7) * 8;
        *(bf16x8*)&T[r][d8] = *(const bf16x8*)&qkv[(size_t)(n0 + r) * LDQKV + 2 * EDIM + h * HD + d8];
    }
    __syncthreads();
    // lane -> d mapping: LDS column reads hit 32 consecutive dwords (conflict-free)
    #pragma unroll
    for (int c = tid; c < 512; c += 256) {
        const int d = c & 63, k8 = (c >> 6) * 8;
        bf16x8 v;
        #pragma unroll
        for (int j = 0; j < 8; j++) v[j] = T[k8 + j][d];
        *(bf16x8*)&vt[(size_t)(h * HD + d) * N_TOK + n0 + k8] = v;
    }
}

// ---------------- flash attention with step mask (V pre-transposed) ----------------
__global__ __launch_bounds__(256) void attn_kernel(const __bf16* __restrict__ qkv,
                                                   const __bf16* __restrict__ vt,
                                                   const int* __restrict__ steps,
                                                   __bf16* __restrict__ ctx) {
    __shared__ __attribute__((aligned(16))) __bf16 Ks[128][72];   // [key][d]
    __shared__ __attribute__((aligned(16))) __bf16 Vs[64][136];   // [d][key]
    __shared__ __attribute__((aligned(16))) __bf16 Ps[64][136];   // [q][key]
    __shared__ int kst[128];

    const int h = blockIdx.y;
    const int tid = threadIdx.x, wave = tid >> 6, lane = tid & 63;
    const int lr = lane & 15, lq = lane >> 4;
    const int qbase = blockIdx.x * 64 + wave * 16;
    const float SC = 0.125f * 1.44269504f;   // 1/sqrt(64) * log2(e)

    bf16x8 aq[2];
    {
        const __bf16* qrow = qkv + (size_t)(qbase + lr) * LDQKV + h * HD;
        aq[0] = *(const bf16x8*)&qrow[lq * 8];
        aq[1] = *(const bf16x8*)&qrow[32 + lq * 8];
    }
    int qstep[4];
    #pragma unroll
    for (int r = 0; r < 4; r++) qstep[r] = steps[qbase + lq * 4 + r];

    float m_i[4], l_i[4];
    #pragma unroll
    for (int r = 0; r < 4; r++) { m_i[r] = -3e38f; l_i[r] = 0.f; }
    f32x4 o[4] = {};

    for (int kt = 0; kt < N_TOK; kt += 128) {
        __syncthreads();
        // stage K tile [128][64] (vector copies)
        #pragma unroll
        for (int c = tid; c < 1024; c += 256) {
            const int row = c >> 3, k8 = (c & 7) * 8;
            *(bf16x8*)&Ks[row][k8] =
                *(const bf16x8*)&qkv[(size_t)(kt + row) * LDQKV + EDIM + h * HD + k8];
        }
        // stage V^T tile [64][128] from pre-transposed global (vector copies)
        #pragma unroll
        for (int c = tid; c < 1024; c += 256) {
            const int d = c >> 4, k8 = (c & 15) * 8;
            *(bf16x8*)&Vs[d][k8] = *(const bf16x8*)&vt[(size_t)(h * HD + d) * N_TOK + kt + k8];
        }
        if (tid < 128) kst[tid] = steps[kt + tid];
        __syncthreads();

        // S = Q K^T (base-2 scaled)
        f32x4 s[8];
        #pragma unroll
        for (int t = 0; t < 8; t++) {
            bf16x8 b0 = *(const bf16x8*)&Ks[t * 16 + lr][lq * 8];
            bf16x8 b1 = *(const bf16x8*)&Ks[t * 16 + lr][32 + lq * 8];
            f32x4 a = {};
            a = __builtin_amdgcn_mfma_f32_16x16x32_bf16(aq[0], b0, a, 0, 0, 0);
            a = __builtin_amdgcn_mfma_f32_16x16x32_bf16(aq[1], b1, a, 0, 0, 0);
            s[t] = a;
        }
        float mnew[4];
        #pragma unroll
        for (int r = 0; r < 4; r++) mnew[r] = m_i[r];
        #pragma unroll
        for (int t = 0; t < 8; t++) {
            const int kstep = kst[t * 16 + lr];
            #pragma unroll
            for (int r = 0; r < 4; r++) {
                float v = s[t][r] * SC;
                if (kstep < qstep[r]) v = -1e9f;
                s[t][r] = v;
                mnew[r] = fmaxf(mnew[r], v);
            }
        }
        #pragma unroll
        for (int r = 0; r < 4; r++) {
            float v = mnew[r];
            v = fmaxf(v, __shfl_xor(v, 1));
            v = fmaxf(v, __shfl_xor(v, 2));
            v = fmaxf(v, __shfl_xor(v, 4));
            v = fmaxf(v, __shfl_xor(v, 8));
            mnew[r] = v;
        }
        #pragma unroll
        for (int r = 0; r < 4; r++) {
            const float a = exp2f(m_i[r] - mnew[r]);
            m_i[r] = mnew[r];
            float sum = 0.f;
            #pragma unroll
            for (int t = 0; t < 8; t++) {
                const float p = exp2f(s[t][r] - mnew[r]);
                s[t][r] = p;
                sum += p;
            }
            sum += __shfl_xor(sum, 1);
            sum += __shfl_xor(sum, 2);
            sum += __shfl_xor(sum, 4);
            sum += __shfl_xor(sum, 8);
            l_i[r] = l_i[r] * a + sum;
            #pragma unroll
            for (int dt = 0; dt < 4; dt++) o[dt][r] *= a;
        }
        // P (C-layout) -> LDS band
        #pragma unroll
        for (int t = 0; t < 8; t++)
            #pragma unroll
            for (int r = 0; r < 4; r++)
                Ps[wave * 16 + lq * 4 + r][t * 16 + lr] = (__bf16)s[t][r];
        // O += P V
        #pragma unroll
        for (int ks2 = 0; ks2 < 4; ks2++) {
            bf16x8 ap = *(const bf16x8*)&Ps[wave * 16 + lr][ks2 * 32 + lq * 8];
            #pragma unroll
            for (int dt = 0; dt < 4; dt++) {
                bf16x8 bv = *(const bf16x8*)&Vs[dt * 16 + lr][ks2 * 32 + lq * 8];
                o[dt] = __builtin_amdgcn_mfma_f32_16x16x32_bf16(ap, bv, o[dt], 0, 0, 0);
            }
        }
    }
    #pragma unroll
    for (int dt = 0; dt < 4; dt++)
        #pragma unroll
        for (int r = 0; r < 4; r++) {
            const float v = o[dt][r] / l_i[r];
            ctx[(size_t)(qbase + lq * 4 + r) * EDIM + h * HD + dt * 16 + lr] = (__bf16)v;
        }
}

// ---------------- embeddings: combined cols [512, 896) ----------------
__global__ void embed_kernel(const int* __restrict__ dmask, const int* __restrict__ steps,
                             const float* __restrict__ status, __bf16* __restrict__ combined) {
    const int n = blockIdx.x;
    const int c = threadIdx.x;               // 0..383
    const int st = min(max(steps[n], 0), 99);
    float v;
    if (c < 128) {
        v = status[dmask[n] * 128 + c];
    } else {
        const int c2 = c - 128;
        const int p = c2 >> 1;
        const float div = expf((float)(2 * p) * (-9.210340371976184f / 256.0f));
        const float ang = (float)st * div;
        v = (c2 & 1) ? cosf(ang) : sinf(ang);
    }
    combined[(size_t)n * LDCOMB + EDIM + c] = (__bf16)v;
}

// ---------------- LayerNorm + ReLU + residual ----------------
__global__ __launch_bounds__(256) void ln_kernel(const float* __restrict__ h,
                                                 const float* __restrict__ x,
                                                 const float* __restrict__ gamma,
                                                 const float* __restrict__ beta,
                                                 float* __restrict__ out) {
    const int row = blockIdx.x * 4 + (threadIdx.x >> 6);
    const int lane = threadIdx.x & 63;
    const float* hr = h + (size_t)row * EDIM;
    float4 v0 = ((const float4*)hr)[lane];
    float4 v1 = ((const float4*)hr)[64 + lane];
    float sum = v0.x + v0.y + v0.z + v0.w + v1.x + v1.y + v1.z + v1.w;
    float sq = v0.x * v0.x + v0.y * v0.y + v0.z * v0.z + v0.w * v0.w +
               v1.x * v1.x + v1.y * v1.y + v1.z * v1.z + v1.w * v1.w;
    #pragma unroll
    for (int m = 1; m < 64; m <<= 1) {
        sum += __shfl_xor(sum, m);
        sq  += __shfl_xor(sq, m);
    }
    const float mean = sum * (1.0f / EDIM);
    const float var = sq * (1.0f / EDIM) - mean * mean;
    const float rstd = rsqrtf(var + 1e-5f);
    const float* xr = x + (size_t)row * EDIM;
    float* orow = out + (size_t)row * EDIM;
    #pragma unroll
    for (int half = 0; half < 2; half++) {
        const float4 v = half ? v1 : v0;
        const int cb = half * 256 + lane * 4;
        float4 res;
        const float* vp = (const float*)&v;
        float tmp[4];
        #pragma unroll
        for (int i = 0; i < 4; i++) {
            const int c = cb + i;
            float t = (vp[i] - mean) * rstd * gamma[c] + beta[c];
            t = fmaxf(t, 0.f);
            tmp[i] = xr[c] + t;
        }
        res.x = tmp[0]; res.y = tmp[1]; res.z = tmp[2]; res.w = tmp[3];
        ((float4*)orow)[cb >> 2] = res;
    }
}

// ---------------- launch ----------------
extern "C" void kernel_launch(void* const* d_in, const int* in_sizes, int n_in,
                              void* d_out, int out_size, void* d_ws, size_t ws_size,
                              hipStream_t stream) {
    const float* x      = (const float*)d_in[0];
    const int*   dmask  = (const int*)d_in[1];
    const int*   steps  = (const int*)d_in[2];
    const float* status = (const float*)d_in[3];
    const float* w_in   = (const float*)d_in[4];
    const float* b_in   = (const float*)d_in[5];
    const float* w_out  = (const float*)d_in[6];
    const float* b_out  = (const float*)d_in[7];
    const float* w_mlp  = (const float*)d_in[8];
    const float* b_mlp  = (const float*)d_in[9];
    const float* gamma  = (const float*)d_in[10];
    const float* beta   = (const float*)d_in[11];
    float* out = (float*)d_out;

    char* ws = (char*)d_ws;
    size_t off = 0;
    auto alloc = [&](size_t bytes) {
        void* p = ws + off;
        off = (off + bytes + 255) & ~(size_t)255;
        return p;
    };
    __bf16* x_bf    = (__bf16*)alloc((size_t)N_TOK * EDIM * 2);
    __bf16* wqkv_bf = (__bf16*)alloc((size_t)3 * EDIM * EDIM * 2);
    __bf16* wout_bf = (__bf16*)alloc((size_t)EDIM * EDIM * 2);
    __bf16* wmlp_bf = (__bf16*)alloc((size_t)EDIM * LDCOMB * 2);
    __bf16* qkv_bf  = (__bf16*)alloc((size_t)N_TOK * LDQKV * 2);
    __bf16* vt_bf   = (__bf16*)alloc((size_t)EDIM * N_TOK * 2);
    __bf16* ctx_bf  = (__bf16*)alloc((size_t)N_TOK * EDIM * 2);
    __bf16* comb_bf = (__bf16*)alloc((size_t)N_TOK * LDCOMB * 2);
    float*  h_f32   = (float*)alloc((size_t)N_TOK * EDIM * 4);

    // fused converts
    {
        const int n0 = N_TOK * EDIM / 4;
        const int n1 = 3 * EDIM * EDIM / 4;
        const int n2 = EDIM * EDIM / 4;
        const int n3 = EDIM * LDCOMB / 4;
        const int tot = n0 + n1 + n2 + n3;
        cvt4_kernel<<<(tot + 255) / 256, 256, 0, stream>>>(
            x, x_bf, n0, w_in, wqkv_bf, n1, w_out, wout_bf, n2, w_mlp, wmlp_bf, n3);
    }
    // qkv = x @ w_in^T + b_in
    gemm_nt<1><<<dim3(N_TOK / 128, 3 * EDIM / 128), 256, 0, stream>>>(
        x_bf, EDIM, wqkv_bf, EDIM, b_in, qkv_bf, LDQKV, EDIM);
    // V transpose
    transpose_v<<<dim3(N_TOK / 64, NHEAD), 256, 0, stream>>>(qkv_bf, vt_bf);
    // attention
    attn_kernel<<<dim3(N_TOK / 64, NHEAD), 256, 0, stream>>>(qkv_bf, vt_bf, steps, ctx_bf);
    // out proj
    gemm_nt<1><<<dim3(N_TOK / 128, EDIM / 128), 256, 0, stream>>>(
        ctx_bf, EDIM, wout_bf, EDIM, b_out, comb_bf, LDCOMB, EDIM);
    // embeddings
    embed_kernel<<<N_TOK, 384, 0, stream>>>(dmask, steps, status, comb_bf);
    // mlp
    gemm_nt<0><<<dim3(N_TOK / 128, EDIM / 128), 256, 0, stream>>>(
        comb_bf, LDCOMB, wmlp_bf, LDCOMB, b_mlp, h_f32, EDIM, LDCOMB);
    // LN + ReLU + residual
    ln_kernel<<<N_TOK / 4, 256, 0, stream>>>(h_f32, x, gamma, beta, out);
}

// Round 3
// 295.816 us; speedup vs baseline: 1.1151x; 1.0490x over previous
//
#include <hip/hip_runtime.h>
#include <hip/hip_bf16.h>
#include <math.h>

typedef __bf16 bf16x8 __attribute__((ext_vector_type(8)));
typedef __bf16 bf16x4 __attribute__((ext_vector_type(4)));
typedef float f32x4 __attribute__((ext_vector_type(4)));

#define N_TOK 4096
#define EDIM 512
#define NHEAD 8
#define HD 64
#define LDQKV 1536
#define LDCOMB 896
#define NBIN 100

// ---------------- fp32 -> bf16 convert, 4 arrays fused ----------------
__global__ void cvt4_kernel(const float* __restrict__ s0, __bf16* __restrict__ d0, int n0,
                            const float* __restrict__ s1, __bf16* __restrict__ d1, int n1,
                            const float* __restrict__ s2, __bf16* __restrict__ d2, int n2,
                            const float* __restrict__ s3, __bf16* __restrict__ d3, int n3) {
    int i = blockIdx.x * blockDim.x + threadIdx.x;
    const float* src; __bf16* dst;
    if (i < n0)                { src = s0; dst = d0; }
    else if (i < n0 + n1)      { i -= n0; src = s1; dst = d1; }
    else if (i < n0 + n1 + n2) { i -= n0 + n1; src = s2; dst = d2; }
    else if (i < n0 + n1 + n2 + n3) { i -= n0 + n1 + n2; src = s3; dst = d3; }
    else return;
    const float4 v = ((const float4*)src)[i];
    bf16x4 o;
    o[0] = (__bf16)v.x; o[1] = (__bf16)v.y; o[2] = (__bf16)v.z; o[3] = (__bf16)v.w;
    ((bf16x4*)dst)[i] = o;
}

// ---------------- generic NT bf16 MFMA GEMM: C = A * B^T + bias ----------------
template<int OUT_MODE>
__global__ __launch_bounds__(256) void gemm_nt(const __bf16* __restrict__ A, int lda,
                                               const __bf16* __restrict__ B, int ldb,
                                               const float* __restrict__ bias,
                                               void* __restrict__ C, int ldc,
                                               int K) {
    __shared__ __attribute__((aligned(16))) __bf16 As[128][40];
    __shared__ __attribute__((aligned(16))) __bf16 Bs[128][40];
    const int tid = threadIdx.x;
    const int wave = tid >> 6, lane = tid & 63;
    const int wm = (wave >> 1) * 64, wn = (wave & 1) * 64;
    const int bm = blockIdx.x * 128, bn = blockIdx.y * 128;
    const int lr = lane & 15, lq = lane >> 4;

    f32x4 acc[4][4] = {};

    for (int k0 = 0; k0 < K; k0 += 32) {
        __syncthreads();
        #pragma unroll
        for (int c = tid; c < 512; c += 256) {
            const int row = c >> 2, k8 = (c & 3) * 8;
            *(bf16x8*)&As[row][k8] = *(const bf16x8*)&A[(size_t)(bm + row) * lda + k0 + k8];
            *(bf16x8*)&Bs[row][k8] = *(const bf16x8*)&B[(size_t)(bn + row) * ldb + k0 + k8];
        }
        __syncthreads();
        bf16x8 af[4], bfr[4];
        #pragma unroll
        for (int i = 0; i < 4; i++) {
            af[i]  = *(const bf16x8*)&As[wm + i * 16 + lr][lq * 8];
            bfr[i] = *(const bf16x8*)&Bs[wn + i * 16 + lr][lq * 8];
        }
        #pragma unroll
        for (int i = 0; i < 4; i++)
            #pragma unroll
            for (int j = 0; j < 4; j++)
                acc[i][j] = __builtin_amdgcn_mfma_f32_16x16x32_bf16(af[i], bfr[j], acc[i][j], 0, 0, 0);
    }

    #pragma unroll
    for (int i = 0; i < 4; i++) {
        #pragma unroll
        for (int j = 0; j < 4; j++) {
            const int col = bn + wn + j * 16 + lr;
            const float bv = bias[col];
            #pragma unroll
            for (int r = 0; r < 4; r++) {
                const int row = bm + wm + i * 16 + lq * 4 + r;
                const float v = acc[i][j][r] + bv;
                if (OUT_MODE == 0) ((float*)C)[(size_t)row * ldc + col] = v;
                else               ((__bf16*)C)[(size_t)row * ldc + col] = (__bf16)v;
            }
        }
    }
}

// ---------------- counting sort by step (100 bins), single block ----------------
__global__ __launch_bounds__(1024) void sort_kernel(const int* __restrict__ steps,
                                                    int* __restrict__ perm,
                                                    int* __restrict__ sstep,
                                                    int* __restrict__ bin_start) {
    __shared__ int hist[NBIN];
    __shared__ int offs[NBIN];
    const int tid = threadIdx.x;
    if (tid < NBIN) hist[tid] = 0;
    __syncthreads();
    for (int i = tid; i < N_TOK; i += 1024)
        atomicAdd(&hist[min(max(steps[i], 0), NBIN - 1)], 1);
    __syncthreads();
    if (tid == 0) {
        int acc = 0;
        for (int s = 0; s < NBIN; s++) { offs[s] = acc; acc += hist[s]; }
    }
    __syncthreads();
    if (tid < NBIN) bin_start[tid] = offs[tid];
    __syncthreads();
    for (int i = tid; i < N_TOK; i += 1024) {
        const int s = min(max(steps[i], 0), NBIN - 1);
        const int pos = atomicAdd(&offs[s], 1);
        perm[pos] = i;
        sstep[pos] = s;
    }
}

// ---------------- gather sorted Q (prescaled), K compact, V^T ----------------
__global__ __launch_bounds__(256) void gather_kernel(const __bf16* __restrict__ qkv,
                                                     const int* __restrict__ perm,
                                                     __bf16* __restrict__ qs,
                                                     __bf16* __restrict__ ks,
                                                     __bf16* __restrict__ vt) {
    __shared__ __attribute__((aligned(16))) __bf16 T[64][72];
    __shared__ int pr[64];
    const int h = blockIdx.y;
    const int n0 = blockIdx.x * 64;
    const int tid = threadIdx.x;
    if (tid < 64) pr[tid] = perm[n0 + tid];
    __syncthreads();
    const float SC = 0.125f * 1.44269504f;   // 1/sqrt(64) * log2(e)
    #pragma unroll
    for (int c = tid; c < 512; c += 256) {
        const int r = c >> 3, d8 = (c & 7) * 8;
        const size_t src = (size_t)pr[r] * LDQKV + h * HD + d8;
        bf16x8 q = *(const bf16x8*)&qkv[src];
        #pragma unroll
        for (int j = 0; j < 8; j++) q[j] = (__bf16)((float)q[j] * SC);
        *(bf16x8*)&qs[(size_t)(n0 + r) * EDIM + h * HD + d8] = q;
        *(bf16x8*)&ks[(size_t)(n0 + r) * EDIM + h * HD + d8] =
            *(const bf16x8*)&qkv[src + EDIM];
        *(bf16x8*)&T[r][d8] = *(const bf16x8*)&qkv[src + 2 * EDIM];
    }
    __syncthreads();
    #pragma unroll
    for (int c = tid; c < 512; c += 256) {
        const int d = c & 63, k8 = (c >> 6) * 8;
        bf16x8 v;
        #pragma unroll
        for (int j = 0; j < 8; j++) v[j] = T[k8 + j][d];
        *(bf16x8*)&vt[(size_t)(h * HD + d) * N_TOK + n0 + k8] = v;
    }
}

// ---------------- flash attention in sorted order with suffix skip ----------------
__global__ __launch_bounds__(256) void attn_kernel(const __bf16* __restrict__ qs,
                                                   const __bf16* __restrict__ ks,
                                                   const __bf16* __restrict__ vt,
                                                   const int* __restrict__ sstep,
                                                   const int* __restrict__ bin_start,
                                                   const int* __restrict__ perm,
                                                   __bf16* __restrict__ ctx) {
    __shared__ __attribute__((aligned(16))) __bf16 Ks[128][72];   // [key][d]
    __shared__ __attribute__((aligned(16))) __bf16 Vs[64][136];   // [d][key]
    __shared__ __attribute__((aligned(16))) __bf16 Ps[64][136];   // [q][key]
    __shared__ int kst[128];

    const int h = blockIdx.y;
    // load-balance: pair qtile x with 63-x across co-resident dispatch waves
    const int qtile = (h < 4) ? blockIdx.x : (63 - blockIdx.x);
    const int tid = threadIdx.x, wave = tid >> 6, lane = tid & 63;
    const int lr = lane & 15, lq = lane >> 4;
    const int qbase = qtile * 64 + wave * 16;

    // K-loop start: all keys before bin_start[min step in block] are blocked
    const int q0step = sstep[qtile * 64];
    const int kt0 = bin_start[q0step] & ~127;

    bf16x8 aq[2];
    {
        const __bf16* qrow = qs + (size_t)(qbase + lr) * EDIM + h * HD;
        aq[0] = *(const bf16x8*)&qrow[lq * 8];
        aq[1] = *(const bf16x8*)&qrow[32 + lq * 8];
    }
    int qstep[4];
    #pragma unroll
    for (int r = 0; r < 4; r++) qstep[r] = sstep[qbase + lq * 4 + r];

    float m_i[4], l_i[4];
    #pragma unroll
    for (int r = 0; r < 4; r++) { m_i[r] = -3e38f; l_i[r] = 0.f; }
    f32x4 o[4] = {};

    for (int kt = kt0; kt < N_TOK; kt += 128) {
        __syncthreads();
        #pragma unroll
        for (int c = tid; c < 1024; c += 256) {
            const int row = c >> 3, k8 = (c & 7) * 8;
            *(bf16x8*)&Ks[row][k8] =
                *(const bf16x8*)&ks[(size_t)(kt + row) * EDIM + h * HD + k8];
        }
        #pragma unroll
        for (int c = tid; c < 1024; c += 256) {
            const int d = c >> 4, k8 = (c & 15) * 8;
            *(bf16x8*)&Vs[d][k8] = *(const bf16x8*)&vt[(size_t)(h * HD + d) * N_TOK + kt + k8];
        }
        if (tid < 128) kst[tid] = sstep[kt + tid];
        __syncthreads();

        // S = Q K^T (Q pre-scaled into base-2 domain)
        f32x4 s[8];
        #pragma unroll
        for (int t = 0; t < 8; t++) {
            bf16x8 b0 = *(const bf16x8*)&Ks[t * 16 + lr][lq * 8];
            bf16x8 b1 = *(const bf16x8*)&Ks[t * 16 + lr][32 + lq * 8];
            f32x4 a = {};
            a = __builtin_amdgcn_mfma_f32_16x16x32_bf16(aq[0], b0, a, 0, 0, 0);
            a = __builtin_amdgcn_mfma_f32_16x16x32_bf16(aq[1], b1, a, 0, 0, 0);
            s[t] = a;
        }
        float mnew[4];
        #pragma unroll
        for (int r = 0; r < 4; r++) mnew[r] = m_i[r];
        #pragma unroll
        for (int t = 0; t < 8; t++) {
            const int kstep = kst[t * 16 + lr];
            #pragma unroll
            for (int r = 0; r < 4; r++) {
                float v = s[t][r];
                if (kstep < qstep[r]) v = -1e9f;
                s[t][r] = v;
                mnew[r] = fmaxf(mnew[r], v);
            }
        }
        #pragma unroll
        for (int r = 0; r < 4; r++) {
            float v = mnew[r];
            v = fmaxf(v, __shfl_xor(v, 1));
            v = fmaxf(v, __shfl_xor(v, 2));
            v = fmaxf(v, __shfl_xor(v, 4));
            v = fmaxf(v, __shfl_xor(v, 8));
            mnew[r] = v;
        }
        #pragma unroll
        for (int r = 0; r < 4; r++) {
            const float a = exp2f(m_i[r] - mnew[r]);
            m_i[r] = mnew[r];
            float sum = 0.f;
            #pragma unroll
            for (int t = 0; t < 8; t++) {
                const float p = exp2f(s[t][r] - mnew[r]);
                s[t][r] = p;
                sum += p;
            }
            sum += __shfl_xor(sum, 1);
            sum += __shfl_xor(sum, 2);
            sum += __shfl_xor(sum, 4);
            sum += __shfl_xor(sum, 8);
            l_i[r] = l_i[r] * a + sum;
            #pragma unroll
            for (int dt = 0; dt < 4; dt++) o[dt][r] *= a;
        }
        #pragma unroll
        for (int t = 0; t < 8; t++)
            #pragma unroll
            for (int r = 0; r < 4; r++)
                Ps[wave * 16 + lq * 4 + r][t * 16 + lr] = (__bf16)s[t][r];
        #pragma unroll
        for (int ks2 = 0; ks2 < 4; ks2++) {
            bf16x8 ap = *(const bf16x8*)&Ps[wave * 16 + lr][ks2 * 32 + lq * 8];
            #pragma unroll
            for (int dt = 0; dt < 4; dt++) {
                bf16x8 bv = *(const bf16x8*)&Vs[dt * 16 + lr][ks2 * 32 + lq * 8];
                o[dt] = __builtin_amdgcn_mfma_f32_16x16x32_bf16(ap, bv, o[dt], 0, 0, 0);
            }
        }
    }
    // scatter back to original token order
    int orow[4];
    #pragma unroll
    for (int r = 0; r < 4; r++) orow[r] = perm[qbase + lq * 4 + r];
    #pragma unroll
    for (int dt = 0; dt < 4; dt++)
        #pragma unroll
        for (int r = 0; r < 4; r++) {
            const float v = o[dt][r] / l_i[r];
            ctx[(size_t)orow[r] * EDIM + h * HD + dt * 16 + lr] = (__bf16)v;
        }
}

// ---------------- time-encoding table [100][256] ----------------
__global__ void timetab_kernel(__bf16* __restrict__ tab) {
    const int st = blockIdx.x;   // 0..99
    const int c = threadIdx.x;   // 0..255
    const int p = c >> 1;
    const float div = expf((float)(2 * p) * (-9.210340371976184f / 256.0f));
    const float ang = (float)st * div;
    tab[st * 256 + c] = (__bf16)((c & 1) ? cosf(ang) : sinf(ang));
}

// ---------------- embeddings: combined cols [512, 896) ----------------
__global__ void embed_kernel(const int* __restrict__ dmask, const int* __restrict__ steps,
                             const float* __restrict__ status, const __bf16* __restrict__ tab,
                             __bf16* __restrict__ combined) {
    const int n = blockIdx.x;
    const int c = threadIdx.x;               // 0..383
    __bf16 v;
    if (c < 128) {
        v = (__bf16)status[dmask[n] * 128 + c];
    } else {
        const int st = min(max(steps[n], 0), NBIN - 1);
        v = tab[st * 256 + (c - 128)];
    }
    combined[(size_t)n * LDCOMB + EDIM + c] = v;
}

// ---------------- LayerNorm + ReLU + residual ----------------
__global__ __launch_bounds__(256) void ln_kernel(const float* __restrict__ h,
                                                 const float* __restrict__ x,
                                                 const float* __restrict__ gamma,
                                                 const float* __restrict__ beta,
                                                 float* __restrict__ out) {
    const int row = blockIdx.x * 4 + (threadIdx.x >> 6);
    const int lane = threadIdx.x & 63;
    const float* hr = h + (size_t)row * EDIM;
    float4 v0 = ((const float4*)hr)[lane];
    float4 v1 = ((const float4*)hr)[64 + lane];
    float sum = v0.x + v0.y + v0.z + v0.w + v1.x + v1.y + v1.z + v1.w;
    float sq = v0.x * v0.x + v0.y * v0.y + v0.z * v0.z + v0.w * v0.w +
               v1.x * v1.x + v1.y * v1.y + v1.z * v1.z + v1.w * v1.w;
    #pragma unroll
    for (int m = 1; m < 64; m <<= 1) {
        sum += __shfl_xor(sum, m);
        sq  += __shfl_xor(sq, m);
    }
    const float mean = sum * (1.0f / EDIM);
    const float var = sq * (1.0f / EDIM) - mean * mean;
    const float rstd = rsqrtf(var + 1e-5f);
    const float* xr = x + (size_t)row * EDIM;
    float* orow = out + (size_t)row * EDIM;
    #pragma unroll
    for (int half = 0; half < 2; half++) {
        const float4 v = half ? v1 : v0;
        const int cb = half * 256 + lane * 4;
        float4 res;
        const float* vp = (const float*)&v;
        float tmp[4];
        #pragma unroll
        for (int i = 0; i < 4; i++) {
            const int c = cb + i;
            float t = (vp[i] - mean) * rstd * gamma[c] + beta[c];
            t = fmaxf(t, 0.f);
            tmp[i] = xr[c] + t;
        }
        res.x = tmp[0]; res.y = tmp[1]; res.z = tmp[2]; res.w = tmp[3];
        ((float4*)orow)[cb >> 2] = res;
    }
}

// ---------------- launch ----------------
extern "C" void kernel_launch(void* const* d_in, const int* in_sizes, int n_in,
                              void* d_out, int out_size, void* d_ws, size_t ws_size,
                              hipStream_t stream) {
    const float* x      = (const float*)d_in[0];
    const int*   dmask  = (const int*)d_in[1];
    const int*   steps  = (const int*)d_in[2];
    const float* status = (const float*)d_in[3];
    const float* w_in   = (const float*)d_in[4];
    const float* b_in   = (const float*)d_in[5];
    const float* w_out  = (const float*)d_in[6];
    const float* b_out  = (const float*)d_in[7];
    const float* w_mlp  = (const float*)d_in[8];
    const float* b_mlp  = (const float*)d_in[9];
    const float* gamma  = (const float*)d_in[10];
    const float* beta   = (const float*)d_in[11];
    float* out = (float*)d_out;

    char* ws = (char*)d_ws;
    size_t off = 0;
    auto alloc = [&](size_t bytes) {
        void* p = ws + off;
        off = (off + bytes + 255) & ~(size_t)255;
        return p;
    };
    __bf16* x_bf    = (__bf16*)alloc((size_t)N_TOK * EDIM * 2);   // reused as qs after qkv GEMM
    __bf16* wqkv_bf = (__bf16*)alloc((size_t)3 * EDIM * EDIM * 2);
    __bf16* wout_bf = (__bf16*)alloc((size_t)EDIM * EDIM * 2);
    __bf16* wmlp_bf = (__bf16*)alloc((size_t)EDIM * LDCOMB * 2);
    __bf16* qkv_bf  = (__bf16*)alloc((size_t)N_TOK * LDQKV * 2);
    __bf16* ks_bf   = (__bf16*)alloc((size_t)N_TOK * EDIM * 2);
    __bf16* vt_bf   = (__bf16*)alloc((size_t)EDIM * N_TOK * 2);
    __bf16* ctx_bf  = (__bf16*)alloc((size_t)N_TOK * EDIM * 2);
    __bf16* comb_bf = (__bf16*)alloc((size_t)N_TOK * LDCOMB * 2);
    float*  h_f32   = (float*)alloc((size_t)N_TOK * EDIM * 4);
    int*    perm    = (int*)alloc(N_TOK * 4);
    int*    sstep   = (int*)alloc(N_TOK * 4);
    int*    binst   = (int*)alloc(NBIN * 4);
    __bf16* tab     = (__bf16*)alloc(NBIN * 256 * 2);
    __bf16* qs_bf   = x_bf;   // alias: x_bf dead after qkv GEMM

    // fused converts
    {
        const int n0 = N_TOK * EDIM / 4;
        const int n1 = 3 * EDIM * EDIM / 4;
        const int n2 = EDIM * EDIM / 4;
        const int n3 = EDIM * LDCOMB / 4;
        const int tot = n0 + n1 + n2 + n3;
        cvt4_kernel<<<(tot + 255) / 256, 256, 0, stream>>>(
            x, x_bf, n0, w_in, wqkv_bf, n1, w_out, wout_bf, n2, w_mlp, wmlp_bf, n3);
    }
    // qkv = x @ w_in^T + b_in
    gemm_nt<1><<<dim3(N_TOK / 128, 3 * EDIM / 128), 256, 0, stream>>>(
        x_bf, EDIM, wqkv_bf, EDIM, b_in, qkv_bf, LDQKV, EDIM);
    // counting sort by step
    sort_kernel<<<1, 1024, 0, stream>>>(steps, perm, sstep, binst);
    // gather sorted Q/K/V^T
    gather_kernel<<<dim3(N_TOK / 64, NHEAD), 256, 0, stream>>>(qkv_bf, perm, qs_bf, ks_bf, vt_bf);
    // attention with suffix skip
    attn_kernel<<<dim3(N_TOK / 64, NHEAD), 256, 0, stream>>>(
        qs_bf, ks_bf, vt_bf, sstep, binst, perm, ctx_bf);
    // out proj
    gemm_nt<1><<<dim3(N_TOK / 128, EDIM / 128), 256, 0, stream>>>(
        ctx_bf, EDIM, wout_bf, EDIM, b_out, comb_bf, LDCOMB, EDIM);
    // time table + embeddings
    timetab_kernel<<<NBIN, 256, 0, stream>>>(tab);
    embed_kernel<<<N_TOK, 384, 0, stream>>>(dmask, steps, status, tab, comb_bf);
    // mlp
    gemm_nt<0><<<dim3(N_TOK / 128, EDIM / 128), 256, 0, stream>>>(
        comb_bf, LDCOMB, wmlp_bf, LDCOMB, b_mlp, h_f32, EDIM, LDCOMB);
    // LN + ReLU + residual
    ln_kernel<<<N_TOK / 4, 256, 0, stream>>>(h_f32, x, gamma, beta, out);
}